// Round 3
// baseline (46.767 us; speedup 1.0000x reference)
//
#include <hip/hip_runtime.h>

// Masked Pearson correlation per row, summed over batch.
// pre, label: [B=32, L=128, N=8192] fp32.  out: [L=128] fp32.
//
// R1: 46.6 us, FETCH_SIZE ~131 MB of 268 MB read -> ~50% random L3 hit.
// R2/R3: deterministic L3 partitioning — rows < SPLIT_ROW use regular loads
//     (pinned resident in 256 MiB Infinity Cache, 160 MiB), rows >= SPLIT_ROW
//     use non-temporal (no-allocate) loads streaming from HBM.

#define THRESH 0.001f

constexpr int B = 32;
constexpr int L = 128;
constexpr int N = 8192;
constexpr int BLOCK = 256;           // multiple of 64 (wave size)
constexpr int ITERS = N / 4 / BLOCK; // 8 float4 loads per input per thread
constexpr int SPLIT_ROW = 2560;      // pinned: 2 arrays * 2560 rows * 32 KiB = 160 MiB

typedef float vfloat4 __attribute__((ext_vector_type(4)));  // native vector for NT builtin

template <bool NT>
__device__ inline void accumulate_row(const float* __restrict__ pre_row,
                                      const float* __restrict__ label_row,
                                      float& cnt, float& sp, float& sl,
                                      float& spp, float& sll, float& spl) {
    const vfloat4* p4 = reinterpret_cast<const vfloat4*>(pre_row);
    const vfloat4* l4 = reinterpret_cast<const vfloat4*>(label_row);
    #pragma unroll
    for (int i = 0; i < ITERS; ++i) {
        const int idx = threadIdx.x + i * BLOCK;  // coalesced
        vfloat4 p, l;
        if (NT) {
            p = __builtin_nontemporal_load(&p4[idx]);
            l = __builtin_nontemporal_load(&l4[idx]);
        } else {
            p = p4[idx];
            l = l4[idx];
        }
        #pragma unroll
        for (int j = 0; j < 4; ++j) {
            const float pj = p[j];
            const float lj = l[j];
            const float m = ((fabsf(pj) > THRESH) || (fabsf(lj) > THRESH)) ? 1.f : 0.f;
            const float pm = pj * m;
            const float lm = lj * m;
            cnt += m;
            sp  += pm;
            sl  += lm;
            spp += pm * pj;
            sll += lm * lj;
            spl += pm * lj;
        }
    }
}

__global__ __launch_bounds__(BLOCK) void cc_row_kernel(const float* __restrict__ pre,
                                                       const float* __restrict__ label,
                                                       float* __restrict__ row_cc) {
    const int row = blockIdx.x;  // row = b*L + l
    const float* prow = pre   + (size_t)row * N;
    const float* lrow = label + (size_t)row * N;

    float cnt = 0.f, sp = 0.f, sl = 0.f, spp = 0.f, sll = 0.f, spl = 0.f;

    if (row < SPLIT_ROW) {
        accumulate_row<false>(prow, lrow, cnt, sp, sl, spp, sll, spl);
    } else {
        accumulate_row<true>(prow, lrow, cnt, sp, sl, spp, sll, spl);
    }

    // Reduce 6 values across the 64-lane wave.
    #pragma unroll
    for (int off = 32; off > 0; off >>= 1) {
        cnt += __shfl_down(cnt, off);
        sp  += __shfl_down(sp,  off);
        sl  += __shfl_down(sl,  off);
        spp += __shfl_down(spp, off);
        sll += __shfl_down(sll, off);
        spl += __shfl_down(spl, off);
    }

    // Reduce across the 4 waves via LDS.
    __shared__ float red[BLOCK / 64][6];
    const int lane = threadIdx.x & 63;
    const int wave = threadIdx.x >> 6;
    if (lane == 0) {
        red[wave][0] = cnt; red[wave][1] = sp;  red[wave][2] = sl;
        red[wave][3] = spp; red[wave][4] = sll; red[wave][5] = spl;
    }
    __syncthreads();

    if (threadIdx.x == 0) {
        float c = 0.f, a = 0.f, b = 0.f, qp = 0.f, ql = 0.f, q = 0.f;
        #pragma unroll
        for (int w = 0; w < BLOCK / 64; ++w) {
            c  += red[w][0]; a  += red[w][1]; b  += red[w][2];
            qp += red[w][3]; ql += red[w][4]; q  += red[w][5];
        }
        const float cov = q  - a * b / c;
        const float vp  = qp - a * a / c;
        const float vl  = ql - b * b / c;
        // Transposed layout [l][b] so the sum kernel reads contiguously.
        const int bi = row >> 7;       // row / L
        const int li = row & (L - 1);  // row % L
        row_cc[li * B + bi] = cov / sqrtf(vp * vl);
    }
}

// out[l] = sum_b row_cc[l*B + b].  Contiguous float4 reads, deterministic.
__global__ __launch_bounds__(L) void cc_sum_kernel(const float* __restrict__ row_cc,
                                                   float* __restrict__ out) {
    const int l = threadIdx.x;
    const float4* v = reinterpret_cast<const float4*>(row_cc + l * B);
    float s = 0.f;
    #pragma unroll
    for (int i = 0; i < B / 4; ++i) {
        const float4 x = v[i];
        s += x.x + x.y + x.z + x.w;
    }
    out[l] = s;
}

extern "C" void kernel_launch(void* const* d_in, const int* in_sizes, int n_in,
                              void* d_out, int out_size, void* d_ws, size_t ws_size,
                              hipStream_t stream) {
    const float* pre   = (const float*)d_in[0];
    const float* label = (const float*)d_in[1];
    float* out    = (float*)d_out;
    float* row_cc = (float*)d_ws;   // 4096 floats = 16 KiB scratch

    cc_row_kernel<<<B * L, BLOCK, 0, stream>>>(pre, label, row_cc);
    cc_sum_kernel<<<1, L, 0, stream>>>(row_cc, out);
}